// Round 1
// baseline (440.409 us; speedup 1.0000x reference)
//
#include <hip/hip_runtime.h>
#include <stdint.h>

#define TROWS 128
#define SMEM_BYTES (65536 + 512 + 512 + 16)

typedef __attribute__((ext_vector_type(8))) short bfrag_t;
typedef __attribute__((ext_vector_type(4))) float f32x4;

static __device__ __forceinline__ unsigned short f2bf(float f) {
  unsigned int u = __float_as_uint(f);
  u += 0x7fffu + ((u >> 16) & 1u);   // round-to-nearest-even
  return (unsigned short)(u >> 16);
}

static __device__ __forceinline__ float tanh_fast(float s) {
  s = fminf(fmaxf(s, -15.f), 15.f);
  float e = __expf(2.f * s);
  return __fdividef(e - 1.f, e + 1.f);
}

// Pre-swizzle W1 (f32 [256][256], k-major) into MFMA B-fragment order, bf16.
// W1f[((cc*8+kk)*64 + lane)*8 + j] = bf16(W1[kk*32 + 8*(lane>>4) + j][cc*16 + (lane&15)])
__global__ void prep_w1_kernel(const float* __restrict__ W1, unsigned short* __restrict__ W1f) {
  const int bx = blockIdx.x;   // cc*8 + kk, 0..127
  const int l = threadIdx.x;   // 0..63
  const int cc = bx >> 3, kk = bx & 7;
  const int h = cc * 16 + (l & 15);
  const int kbase = kk * 32 + ((l >> 4) << 3);
  bfrag_t pk;
#pragma unroll
  for (int j = 0; j < 8; ++j) pk[j] = (short)f2bf(W1[(size_t)(kbase + j) * 256 + h]);
  *(bfrag_t*)(W1f + (size_t)(bx * 64 + l) * 8) = pk;
}

__launch_bounds__(256, 2)
__global__ void attnpool_kernel(const float* __restrict__ x,
                                const int* __restrict__ batch,
                                const unsigned short* __restrict__ W1f,
                                const float* __restrict__ b1,
                                const float* __restrict__ W2,
                                const float* __restrict__ b2,
                                float* __restrict__ out,   // raw weighted sums (zeroed)
                                float* __restrict__ Zp,    // softmax denominator (zeroed)
                                int N) {
  extern __shared__ char smem[];
  short* xs        = (short*)smem;            // [128][256] bf16, XOR-swizzled, 64 KB
  float* w_lds     = (float*)(smem + 65536);  // [128]
  int*   batch_lds = (int*)(smem + 66048);    // [128]
  float* zpart     = (float*)(smem + 66560);  // [4]

  const int t = threadIdx.x;
  const int lane = t & 63;
  const int wv = t >> 6;
  const int l15 = lane & 15;
  const int row0 = blockIdx.x * TROWS;

  // ---- Phase 1: stage x tile f32 -> bf16 -> swizzled LDS ----
#pragma unroll 4
  for (int p = 0; p < 16; ++p) {
    const int row = p * 8 + (t >> 5);
    const int c = t & 31;                  // 8-float chunk within row
    const int row_g = row0 + row;
    f32x4 v0 = {0.f, 0.f, 0.f, 0.f}, v1 = {0.f, 0.f, 0.f, 0.f};
    if (row_g < N) {
      const f32x4* src = (const f32x4*)(x + (size_t)row_g * 256 + c * 8);
      v0 = src[0];
      v1 = src[1];
    }
    bfrag_t pk;
    pk[0] = (short)f2bf(v0[0]); pk[1] = (short)f2bf(v0[1]);
    pk[2] = (short)f2bf(v0[2]); pk[3] = (short)f2bf(v0[3]);
    pk[4] = (short)f2bf(v1[0]); pk[5] = (short)f2bf(v1[1]);
    pk[6] = (short)f2bf(v1[2]); pk[7] = (short)f2bf(v1[3]);
    const int byte = row * 512 + ((c * 16) ^ ((row & 7) << 4));
    *(bfrag_t*)((char*)xs + byte) = pk;
  }
  if (t < TROWS) {
    int rg = row0 + t;
    if (rg >= N) rg = N - 1;
    batch_lds[t] = batch[rg];
  }
  __syncthreads();

  // ---- Phase 2: scores via MFMA. Wave wv owns rows [wv*32, wv*32+32). ----
  bfrag_t afrag[2][8];  // A cached in regs: read LDS once
#pragma unroll
  for (int rf = 0; rf < 2; ++rf) {
    const int row = wv * 32 + rf * 16 + l15;
    const int sw = (row & 7) << 4;
#pragma unroll
    for (int kk = 0; kk < 8; ++kk) {
      const int byte = row * 512 + ((kk * 64 + ((lane >> 4) << 4)) ^ sw);
      afrag[rf][kk] = *(const bfrag_t*)((const char*)xs + byte);
    }
  }

  const float b2c = b2[0];
  float s2p[2][4] = {{0.f, 0.f, 0.f, 0.f}, {0.f, 0.f, 0.f, 0.f}};
  const bfrag_t* Wf = (const bfrag_t*)W1f;

#pragma unroll 2
  for (int cc = 0; cc < 16; ++cc) {
    bfrag_t bfrag[8];
#pragma unroll
    for (int kk = 0; kk < 8; ++kk) bfrag[kk] = Wf[(cc * 8 + kk) * 64 + lane];
    const float b1c = b1[cc * 16 + l15];
    const float w2c = W2[cc * 16 + l15];
    f32x4 acc0 = {0.f, 0.f, 0.f, 0.f}, acc1 = {0.f, 0.f, 0.f, 0.f};
#pragma unroll
    for (int kk = 0; kk < 8; ++kk) {
      acc0 = __builtin_amdgcn_mfma_f32_16x16x32_bf16(afrag[0][kk], bfrag[kk], acc0, 0, 0, 0);
      acc1 = __builtin_amdgcn_mfma_f32_16x16x32_bf16(afrag[1][kk], bfrag[kk], acc1, 0, 0, 0);
    }
    // C/D: row = 4*(lane>>4)+r, col = cc*16 + (lane&15)
#pragma unroll
    for (int r = 0; r < 4; ++r) {
      s2p[0][r] += tanh_fast(acc0[r] + b1c) * w2c;
      s2p[1][r] += tanh_fast(acc1[r] + b1c) * w2c;
    }
  }

  // reduce partial s2 across the 16 lanes of each lane-group; w = exp(score)
#pragma unroll
  for (int rf = 0; rf < 2; ++rf) {
#pragma unroll
    for (int r = 0; r < 4; ++r) {
      float v = s2p[rf][r];
      v += __shfl_xor(v, 1);
      v += __shfl_xor(v, 2);
      v += __shfl_xor(v, 4);
      v += __shfl_xor(v, 8);
      const int row = wv * 32 + rf * 16 + ((lane >> 4) << 2) + r;
      float wr = 0.f;
      if (row0 + row < N) wr = __expf(v + b2c);
      if (l15 == 0) w_lds[row] = wr;
    }
  }
  __syncthreads();

  // ---- Phase 3: Z partial (one atomic per block) ----
  {
    float zv = (t < TROWS) ? w_lds[t] : 0.f;
    zv += __shfl_xor(zv, 1);
    zv += __shfl_xor(zv, 2);
    zv += __shfl_xor(zv, 4);
    zv += __shfl_xor(zv, 8);
    zv += __shfl_xor(zv, 16);
    zv += __shfl_xor(zv, 32);
    if (lane == 0) zpart[wv] = zv;
  }
  __syncthreads();
  if (t == 0) atomicAdd(Zp, zpart[0] + zpart[1] + zpart[2] + zpart[3]);

  // ---- Phase 4: segmented weighted pooling (batch sorted -> uniform branches) ----
  {
    const int half = t >> 7;      // half 0: rows 0..63, half 1: rows 64..127
    const int tt = t & 127;       // column pair: cols 2tt, 2tt+1
    const int rbeg = half * 64;
    float a0 = 0.f, a1 = 0.f;
    int gcur = batch_lds[rbeg];
    for (int r = rbeg; r < rbeg + 64; ++r) {
      const int g = batch_lds[r];
      if (g != gcur) {
        atomicAdd(&out[(size_t)gcur * 256 + 2 * tt], a0);
        atomicAdd(&out[(size_t)gcur * 256 + 2 * tt + 1], a1);
        a0 = 0.f; a1 = 0.f; gcur = g;
      }
      const float wr = w_lds[r];
      const int byte = r * 512 + ((4 * tt) ^ ((r & 7) << 4));
      const unsigned int u = *(const unsigned int*)((const char*)xs + byte);
      a0 += wr * __uint_as_float(u << 16);
      a1 += wr * __uint_as_float(u & 0xffff0000u);
    }
    atomicAdd(&out[(size_t)gcur * 256 + 2 * tt], a0);
    atomicAdd(&out[(size_t)gcur * 256 + 2 * tt + 1], a1);
  }
}

__global__ void finalize_kernel(float* __restrict__ out, const float* __restrict__ Zp, int n4) {
  const int i = blockIdx.x * blockDim.x + threadIdx.x;
  if (i < n4) {
    const float zi = 1.f / Zp[0];
    f32x4* p = (f32x4*)out;
    f32x4 v = p[i];
    v[0] *= zi; v[1] *= zi; v[2] *= zi; v[3] *= zi;
    p[i] = v;
  }
}

extern "C" void kernel_launch(void* const* d_in, const int* in_sizes, int n_in,
                              void* d_out, int out_size, void* d_ws, size_t ws_size,
                              hipStream_t stream) {
  const float* x  = (const float*)d_in[0];
  const int* batch = (const int*)d_in[1];
  const float* W1 = (const float*)d_in[2];
  const float* b1 = (const float*)d_in[3];
  const float* W2 = (const float*)d_in[4];
  const float* b2 = (const float*)d_in[5];
  float* out = (float*)d_out;
  const int N = in_sizes[1];

  unsigned short* W1f = (unsigned short*)d_ws;          // 128 KB
  float* Zp = (float*)((char*)d_ws + 131072);           // 4 B

  static int attr_done = 0;  // host-side only; idempotent attribute, not kernel state
  if (!attr_done) {
    hipFuncSetAttribute((const void*)attnpool_kernel,
                        hipFuncAttributeMaxDynamicSharedMemorySize, SMEM_BYTES);
    attr_done = 1;
  }

  hipMemsetAsync(d_out, 0, (size_t)out_size * sizeof(float), stream);
  hipMemsetAsync(Zp, 0, sizeof(float), stream);
  prep_w1_kernel<<<128, 64, 0, stream>>>(W1, W1f);
  const int nblk = (N + TROWS - 1) / TROWS;
  attnpool_kernel<<<nblk, 256, SMEM_BYTES, stream>>>(x, batch, W1f, b1, W2, b2, out, Zp, N);
  finalize_kernel<<<(out_size / 4 + 255) / 256, 256, 0, stream>>>(out, Zp, out_size / 4);
}

// Round 2
// 409.862 us; speedup vs baseline: 1.0745x; 1.0745x over previous
//
#include <hip/hip_runtime.h>
#include <stdint.h>

#define TROWS 128

typedef __attribute__((ext_vector_type(8))) short bfrag_t;
typedef __attribute__((ext_vector_type(4))) float f32x4;
typedef __attribute__((ext_vector_type(2))) float f32x2;

static __device__ __forceinline__ unsigned short f2bf(float f) {
  unsigned int u = __float_as_uint(f);
  u += 0x7fffu + ((u >> 16) & 1u);   // round-to-nearest-even
  return (unsigned short)(u >> 16);
}

static __device__ __forceinline__ float tanh_fast(float s) {
  s = fminf(fmaxf(s, -15.f), 15.f);
  float e = __expf(2.f * s);
  return __fdividef(e - 1.f, e + 1.f);
}

// Pre-swizzle W1 (f32 [256][256], k-major) into MFMA B-fragment order, bf16.
// W1f[((cc*8+kk)*64 + lane)*8 + j] = bf16(W1[kk*32 + 8*(lane>>4) + j][cc*16 + (lane&15)])
__global__ void prep_w1_kernel(const float* __restrict__ W1, unsigned short* __restrict__ W1f) {
  const int bx = blockIdx.x;   // cc*8 + kk, 0..127
  const int l = threadIdx.x;   // 0..63
  const int cc = bx >> 3, kk = bx & 7;
  const int h = cc * 16 + (l & 15);
  const int kbase = kk * 32 + ((l >> 4) << 3);
  bfrag_t pk;
#pragma unroll
  for (int j = 0; j < 8; ++j) pk[j] = (short)f2bf(W1[(size_t)(kbase + j) * 256 + h]);
  *(bfrag_t*)(W1f + (size_t)(bx * 64 + l) * 8) = pk;
}

__launch_bounds__(256, 3)
__global__ void attnpool_kernel(const float* __restrict__ x,
                                const int* __restrict__ batch,
                                const unsigned short* __restrict__ W1f,
                                const float* __restrict__ b1,
                                const float* __restrict__ W2,
                                const float* __restrict__ b2,
                                float* __restrict__ out,   // raw weighted sums (zeroed)
                                float* __restrict__ Zp,    // softmax denominator (zeroed)
                                int N) {
  __shared__ float w_lds[TROWS];
  __shared__ int   batch_lds[TROWS];
  __shared__ float zpart[4];

  const int t = threadIdx.x;
  const int lane = t & 63;
  const int wv = t >> 6;
  const int l15 = lane & 15;
  const int row0 = blockIdx.x * TROWS;
  const int nvalid = min(TROWS, N - row0);

  if (t < TROWS) {
    int rg = row0 + t;
    if (rg >= N) rg = N - 1;
    batch_lds[t] = batch[rg];
  }

  // ---- Phase 1: A fragments straight from global (f32 -> bf16 in regs) ----
  // A mapping for 16x16x32: row = lane&15, k = kk*32 + (lane>>4)*8 + j
  bfrag_t afrag[2][8];
#pragma unroll
  for (int rf = 0; rf < 2; ++rf) {
    const int row = wv * 32 + rf * 16 + l15;
    const int row_g = row0 + row;
    const float* src = x + (size_t)row_g * 256 + ((lane >> 4) << 3);
    const bool ok = (row_g < N);
#pragma unroll
    for (int kk = 0; kk < 8; ++kk) {
      f32x4 v0 = {0.f, 0.f, 0.f, 0.f}, v1 = {0.f, 0.f, 0.f, 0.f};
      if (ok) {
        v0 = *(const f32x4*)(src + kk * 32);
        v1 = *(const f32x4*)(src + kk * 32 + 4);
      }
      bfrag_t pk;
      pk[0] = (short)f2bf(v0[0]); pk[1] = (short)f2bf(v0[1]);
      pk[2] = (short)f2bf(v0[2]); pk[3] = (short)f2bf(v0[3]);
      pk[4] = (short)f2bf(v1[0]); pk[5] = (short)f2bf(v1[1]);
      pk[6] = (short)f2bf(v1[2]); pk[7] = (short)f2bf(v1[3]);
      afrag[rf][kk] = pk;
    }
  }

  // ---- Phase 2: scores via MFMA; B streamed from L2-resident W1f ----
  const float b2c = b2[0];
  float s2p[2][4] = {{0.f, 0.f, 0.f, 0.f}, {0.f, 0.f, 0.f, 0.f}};
  const bfrag_t* Wf = (const bfrag_t*)W1f;

#pragma unroll 2
  for (int cc = 0; cc < 16; ++cc) {
    bfrag_t bfrag[8];
#pragma unroll
    for (int kk = 0; kk < 8; ++kk) bfrag[kk] = Wf[(cc * 8 + kk) * 64 + lane];
    const float b1c = b1[cc * 16 + l15];
    const float w2c = W2[cc * 16 + l15];
    f32x4 acc0 = {0.f, 0.f, 0.f, 0.f}, acc1 = {0.f, 0.f, 0.f, 0.f};
#pragma unroll
    for (int kk = 0; kk < 8; ++kk) {
      acc0 = __builtin_amdgcn_mfma_f32_16x16x32_bf16(afrag[0][kk], bfrag[kk], acc0, 0, 0, 0);
      acc1 = __builtin_amdgcn_mfma_f32_16x16x32_bf16(afrag[1][kk], bfrag[kk], acc1, 0, 0, 0);
    }
    // C/D: row = 4*(lane>>4)+r, col = cc*16 + (lane&15)
#pragma unroll
    for (int r = 0; r < 4; ++r) {
      s2p[0][r] += tanh_fast(acc0[r] + b1c) * w2c;
      s2p[1][r] += tanh_fast(acc1[r] + b1c) * w2c;
    }
  }

  // reduce partial s2 across the 16 lanes of each lane-group; w = exp(score)
#pragma unroll
  for (int rf = 0; rf < 2; ++rf) {
#pragma unroll
    for (int r = 0; r < 4; ++r) {
      float v = s2p[rf][r];
      v += __shfl_xor(v, 1);
      v += __shfl_xor(v, 2);
      v += __shfl_xor(v, 4);
      v += __shfl_xor(v, 8);
      const int row = wv * 32 + rf * 16 + ((lane >> 4) << 2) + r;
      float wr = 0.f;
      if (row0 + row < N) wr = __expf(v + b2c);
      if (l15 == 0) w_lds[row] = wr;
    }
  }
  __syncthreads();

  // ---- Phase 3: Z partial (one atomic per block) ----
  {
    float zv = (t < TROWS) ? w_lds[t] : 0.f;
    zv += __shfl_xor(zv, 1);
    zv += __shfl_xor(zv, 2);
    zv += __shfl_xor(zv, 4);
    zv += __shfl_xor(zv, 8);
    zv += __shfl_xor(zv, 16);
    zv += __shfl_xor(zv, 32);
    if (lane == 0) zpart[wv] = zv;
  }
  __syncthreads();
  if (t == 0) atomicAdd(Zp, zpart[0] + zpart[1] + zpart[2] + zpart[3]);

  // ---- Phase 4: segmented weighted pooling, x re-read from global (L2-hit) ----
  {
    const int half = t >> 7;      // half 0: rows 0..63, half 1: rows 64..127
    const int tt = t & 127;       // column pair: cols 2tt, 2tt+1
    const int rbeg = half * 64;
    const int rend = min(rbeg + 64, nvalid);
    if (rbeg < nvalid) {
      float a0 = 0.f, a1 = 0.f;
      int gcur = batch_lds[rbeg];
      if (rend == rbeg + 64) {
#pragma unroll 8
        for (int r = rbeg; r < rbeg + 64; ++r) {
          const int g = batch_lds[r];
          if (g != gcur) {
            atomicAdd(&out[(size_t)gcur * 256 + 2 * tt], a0);
            atomicAdd(&out[(size_t)gcur * 256 + 2 * tt + 1], a1);
            a0 = 0.f; a1 = 0.f; gcur = g;
          }
          const float wr = w_lds[r];
          const f32x2 v = *(const f32x2*)(x + (size_t)(row0 + r) * 256 + 2 * tt);
          a0 += wr * v[0];
          a1 += wr * v[1];
        }
      } else {
        for (int r = rbeg; r < rend; ++r) {
          const int g = batch_lds[r];
          if (g != gcur) {
            atomicAdd(&out[(size_t)gcur * 256 + 2 * tt], a0);
            atomicAdd(&out[(size_t)gcur * 256 + 2 * tt + 1], a1);
            a0 = 0.f; a1 = 0.f; gcur = g;
          }
          const float wr = w_lds[r];
          const f32x2 v = *(const f32x2*)(x + (size_t)(row0 + r) * 256 + 2 * tt);
          a0 += wr * v[0];
          a1 += wr * v[1];
        }
      }
      atomicAdd(&out[(size_t)gcur * 256 + 2 * tt], a0);
      atomicAdd(&out[(size_t)gcur * 256 + 2 * tt + 1], a1);
    }
  }
}

__global__ void finalize_kernel(float* __restrict__ out, const float* __restrict__ Zp, int n4) {
  const int i = blockIdx.x * blockDim.x + threadIdx.x;
  if (i < n4) {
    const float zi = 1.f / Zp[0];
    f32x4* p = (f32x4*)out;
    f32x4 v = p[i];
    v[0] *= zi; v[1] *= zi; v[2] *= zi; v[3] *= zi;
    p[i] = v;
  }
}

extern "C" void kernel_launch(void* const* d_in, const int* in_sizes, int n_in,
                              void* d_out, int out_size, void* d_ws, size_t ws_size,
                              hipStream_t stream) {
  const float* x  = (const float*)d_in[0];
  const int* batch = (const int*)d_in[1];
  const float* W1 = (const float*)d_in[2];
  const float* b1 = (const float*)d_in[3];
  const float* W2 = (const float*)d_in[4];
  const float* b2 = (const float*)d_in[5];
  float* out = (float*)d_out;
  const int N = in_sizes[1];

  unsigned short* W1f = (unsigned short*)d_ws;          // 128 KB
  float* Zp = (float*)((char*)d_ws + 131072);           // 4 B

  hipMemsetAsync(d_out, 0, (size_t)out_size * sizeof(float), stream);
  hipMemsetAsync(Zp, 0, sizeof(float), stream);
  prep_w1_kernel<<<128, 64, 0, stream>>>(W1, W1f);
  const int nblk = (N + TROWS - 1) / TROWS;
  attnpool_kernel<<<nblk, 256, 0, stream>>>(x, batch, W1f, b1, W2, b2, out, Zp, N);
  finalize_kernel<<<(out_size / 4 + 255) / 256, 256, 0, stream>>>(out, Zp, out_size / 4);
}

// Round 3
// 278.688 us; speedup vs baseline: 1.5803x; 1.4707x over previous
//
#include <hip/hip_runtime.h>
#include <stdint.h>

#define NBLK 512                 // 2 blocks/CU exactly
#define HR 32                    // rows per half-tile
#define SMEM_BYTES (65536 + 512 + 128 + 256)

typedef __attribute__((ext_vector_type(8))) short bfrag_t;
typedef __attribute__((ext_vector_type(4))) float f32x4;

static __device__ __forceinline__ unsigned short f2bf(float f) {
  unsigned int u = __float_as_uint(f);
  u += 0x7fffu + ((u >> 16) & 1u);   // RNE
  return (unsigned short)(u >> 16);
}

static __device__ __forceinline__ float tanh_fast(float s) {
  // tanh(s) = 1 - 2/(1+e^{2s}); saturates gracefully at +-1, no clamp needed
  float e = __builtin_exp2f(s * 2.8853900817779268f);   // e^{2s}
  float r = __builtin_amdgcn_rcpf(1.f + e);
  return __builtin_fmaf(-2.f, r, 1.f);
}

#define KEEP8(a) asm volatile("" : "+v"(a[0]), "+v"(a[1]), "+v"(a[2]), "+v"(a[3]), \
                                   "+v"(a[4]), "+v"(a[5]), "+v"(a[6]), "+v"(a[7]))

#define GLD16(gp, lp) __builtin_amdgcn_global_load_lds( \
    (const __attribute__((address_space(1))) void*)(gp), \
    (__attribute__((address_space(3))) void*)(lp), 16, 0, 0)

// Pre-swizzle W1 (f32 [256][256], k-major) into MFMA B-fragment order, bf16.
// W1f[((cc*8+kk)*64 + lane)*8 + j] = bf16(W1[kk*32 + 8*(lane>>4) + j][cc*16 + (lane&15)])
__global__ void prep_w1_kernel(const float* __restrict__ W1, unsigned short* __restrict__ W1f) {
  const int bx = blockIdx.x;   // cc*8 + kk, 0..127
  const int l = threadIdx.x;   // 0..63
  const int cc = bx >> 3, kk = bx & 7;
  const int h = cc * 16 + (l & 15);
  const int kbase = kk * 32 + ((l >> 4) << 3);
  bfrag_t pk;
#pragma unroll
  for (int j = 0; j < 8; ++j) pk[j] = (short)f2bf(W1[(size_t)(kbase + j) * 256 + h]);
  *(bfrag_t*)(W1f + (size_t)(bx * 64 + l) * 8) = pk;
}

// read A fragment from swizzled f32 LDS tile, convert to bf16
static __device__ __forceinline__ bfrag_t loadA(const char* buf, int row0l, int kk, int lane) {
  const int row = row0l + (lane & 15);
  const int c0 = kk * 8 + ((lane >> 4) << 1);     // 16B chunk index within row
  const int sw = (row & 7) << 4;
  const char* base = buf + row * 1024;
  const f32x4 v0 = *(const f32x4*)(base + ((c0 * 16) ^ sw));
  const f32x4 v1 = *(const f32x4*)(base + (((c0 + 1) * 16) ^ sw));
  bfrag_t pk;
  pk[0] = (short)f2bf(v0[0]); pk[1] = (short)f2bf(v0[1]);
  pk[2] = (short)f2bf(v0[2]); pk[3] = (short)f2bf(v0[3]);
  pk[4] = (short)f2bf(v1[0]); pk[5] = (short)f2bf(v1[1]);
  pk[6] = (short)f2bf(v1[2]); pk[7] = (short)f2bf(v1[3]);
  return pk;
}

__launch_bounds__(256, 2)
__global__ void attnpool_kernel(const float* __restrict__ x,
                                const int* __restrict__ batch,
                                const unsigned short* __restrict__ W1f,
                                const float* __restrict__ b1,
                                const float* __restrict__ W2,
                                const float* __restrict__ b2,
                                float* __restrict__ out,   // raw weighted sums (zeroed)
                                float* __restrict__ Zp,    // softmax denominator (zeroed)
                                int N) {
  extern __shared__ char smem[];
  char*  xs0   = smem;                          // 32 KB f32 tile, swizzled
  char*  xs1   = smem + 32768;                  // 32 KB f32 tile, swizzled
  float* spart = (float*)(smem + 65536);        // [4][32] per-wave cc-partials
  float* w_lds = (float*)(smem + 66048);        // [32]
  int*   bl    = (int*)(smem + 66176);          // [2][32] graph ids

  const int t = threadIdx.x;
  const int lane = t & 63;
  const int wv = t >> 6;
  const int l15 = lane & 15;

  const int nhalves = (N + HR - 1) / HR;
  const int Hper = (nhalves + NBLK - 1) / NBLK;
  const int h0 = blockIdx.x * Hper;
  const int hend = min(h0 + Hper, nhalves);
  if (h0 >= hend) return;

  // ---- prologue: stage half h0, batch h0; load B-cache + per-lane consts ----
  {
    const size_t rowbase = (size_t)h0 * HR;
#pragma unroll
    for (int i = 0; i < 8; ++i) {
      const int rl = wv * 8 + i;
      size_t grow = rowbase + rl;
      if (grow >= (size_t)N) grow = N - 1;
      const float* src = x + grow * 256 + ((lane ^ (rl & 7)) << 2);
      GLD16(src, xs0 + rl * 1024);
    }
    if (t < HR) {
      size_t grow = rowbase + t;
      if (grow >= (size_t)N) grow = N - 1;
      bl[t] = batch[grow];
    }
  }

  const int cc0 = wv * 4;
  bfrag_t bc[4][8];
  const bfrag_t* Wf = (const bfrag_t*)W1f;
#pragma unroll
  for (int c = 0; c < 4; ++c)
#pragma unroll
    for (int kk = 0; kk < 8; ++kk)
      bc[c][kk] = Wf[((cc0 + c) * 8 + kk) * 64 + lane];

  float b1v[4], w2v[4];
#pragma unroll
  for (int c = 0; c < 4; ++c) {
    b1v[c] = b1[(cc0 + c) * 16 + l15];
    w2v[c] = W2[(cc0 + c) * 16 + l15];
  }
  const float b2c = b2[0];

  float pacc = 0.f;       // pooling accumulator (this thread's column)
  int   gcur = -1;        // current graph id
  float zacc = 0.f;       // block-partial softmax denominator (wave 0)

  __syncthreads();        // drains prologue stage (vmcnt) + batch ds_write

  for (int h = h0; h < hend; ++h) {
    const int cur = (h - h0) & 1;
    char* xc = cur ? xs1 : xs0;
    char* xn = cur ? xs0 : xs1;
    const size_t rowbase = (size_t)h * HR;

    // keep the B-cache pinned in VGPRs across the loop (defeat remat/sink)
    KEEP8(bc[0]); KEEP8(bc[1]); KEEP8(bc[2]); KEEP8(bc[3]);

    // ---- stage next half (fire-and-forget) ----
    if (h + 1 < hend) {
      const size_t rb1 = rowbase + HR;
#pragma unroll
      for (int i = 0; i < 8; ++i) {
        const int rl = wv * 8 + i;
        size_t grow = rb1 + rl;
        if (grow >= (size_t)N) grow = N - 1;
        const float* src = x + grow * 256 + ((lane ^ (rl & 7)) << 2);
        GLD16(src, xn + rl * 1024);
      }
      if (t < HR) {
        size_t grow = rb1 + t;
        if (grow >= (size_t)N) grow = N - 1;
        bl[((cur ^ 1) << 5) + t] = batch[grow];
      }
    }

    // ---- score: kk-outer MFMA (load-A-and-consume, nothing to remat) ----
    f32x4 acc[4][2] = {};
#pragma unroll
    for (int kk = 0; kk < 8; ++kk) {
      const bfrag_t a0 = loadA(xc, 0, kk, lane);
      const bfrag_t a1 = loadA(xc, 16, kk, lane);
#pragma unroll
      for (int c = 0; c < 4; ++c) {
        acc[c][0] = __builtin_amdgcn_mfma_f32_16x16x32_bf16(a0, bc[c][kk], acc[c][0], 0, 0, 0);
        acc[c][1] = __builtin_amdgcn_mfma_f32_16x16x32_bf16(a1, bc[c][kk], acc[c][1], 0, 0, 0);
      }
    }
    float s2p0[4] = {0.f, 0.f, 0.f, 0.f};
    float s2p1[4] = {0.f, 0.f, 0.f, 0.f};
#pragma unroll
    for (int c = 0; c < 4; ++c)
#pragma unroll
      for (int r = 0; r < 4; ++r) {
        s2p0[r] += tanh_fast(acc[c][0][r] + b1v[c]) * w2v[c];
        s2p1[r] += tanh_fast(acc[c][1][r] + b1v[c]) * w2v[c];
      }
    // 16-lane reduce; C/D layout: row = (lane>>4)*4 + r, col = lane&15
#pragma unroll
    for (int r = 0; r < 4; ++r) {
      float v0 = s2p0[r], v1 = s2p1[r];
      v0 += __shfl_xor(v0, 1); v0 += __shfl_xor(v0, 2);
      v0 += __shfl_xor(v0, 4); v0 += __shfl_xor(v0, 8);
      v1 += __shfl_xor(v1, 1); v1 += __shfl_xor(v1, 2);
      v1 += __shfl_xor(v1, 4); v1 += __shfl_xor(v1, 8);
      if (l15 == 0) {
        const int rr = ((lane >> 4) << 2) + r;
        spart[(wv << 5) + rr] = v0;
        spart[(wv << 5) + 16 + rr] = v1;
      }
    }
    __syncthreads();   // spart visible (also drains next-half stage)

    // ---- exp + Z partial (wave 0) ----
    if (wv == 0) {
      float w = 0.f;
      if (lane < HR) {
        const size_t grow = rowbase + lane;
        const float s = spart[lane] + spart[32 + lane] + spart[64 + lane] +
                        spart[96 + lane] + b2c;
        if (grow < (size_t)N) w = __expf(s);
        w_lds[lane] = w;
      }
      float z = w;
      z += __shfl_xor(z, 1);  z += __shfl_xor(z, 2);  z += __shfl_xor(z, 4);
      z += __shfl_xor(z, 8);  z += __shfl_xor(z, 16); z += __shfl_xor(z, 32);
      zacc += z;
    }
    __syncthreads();   // w_lds visible

    // ---- pool: thread t owns column t; running accumulator across halves ----
    {
      const int* blc = bl + (cur << 5);
#pragma unroll
      for (int r = 0; r < HR; ++r) {
        const int g = blc[r];                       // uniform across block
        if (g != gcur) {
          if (gcur >= 0) atomicAdd(&out[(size_t)gcur * 256 + t], pacc);
          pacc = 0.f; gcur = g;
        }
        const float wr = w_lds[r];
        const float xv = *(const float*)(xc + r * 1024 + ((4 * t) ^ ((r & 7) << 4)));
        pacc = __builtin_fmaf(wr, xv, pacc);
      }
    }
    __syncthreads();   // pool done: xc may be overwritten by next stage
  }

  if (gcur >= 0) atomicAdd(&out[(size_t)gcur * 256 + t], pacc);
  if (t == 0) atomicAdd(Zp, zacc);
}

__global__ void finalize_kernel(float* __restrict__ out, const float* __restrict__ Zp, int n4) {
  const int i = blockIdx.x * blockDim.x + threadIdx.x;
  if (i < n4) {
    const float zi = 1.f / Zp[0];
    f32x4* p = (f32x4*)out;
    f32x4 v = p[i];
    v[0] *= zi; v[1] *= zi; v[2] *= zi; v[3] *= zi;
    p[i] = v;
  }
}

extern "C" void kernel_launch(void* const* d_in, const int* in_sizes, int n_in,
                              void* d_out, int out_size, void* d_ws, size_t ws_size,
                              hipStream_t stream) {
  const float* x  = (const float*)d_in[0];
  const int* batch = (const int*)d_in[1];
  const float* W1 = (const float*)d_in[2];
  const float* b1 = (const float*)d_in[3];
  const float* W2 = (const float*)d_in[4];
  const float* b2 = (const float*)d_in[5];
  float* out = (float*)d_out;
  const int N = in_sizes[1];

  unsigned short* W1f = (unsigned short*)d_ws;          // 128 KB
  float* Zp = (float*)((char*)d_ws + 131072);           // 4 B

  static int attr_done = 0;  // host-side only; idempotent attribute, not kernel state
  if (!attr_done) {
    hipFuncSetAttribute((const void*)attnpool_kernel,
                        hipFuncAttributeMaxDynamicSharedMemorySize, SMEM_BYTES);
    attr_done = 1;
  }

  hipMemsetAsync(d_out, 0, (size_t)out_size * sizeof(float), stream);
  hipMemsetAsync(Zp, 0, sizeof(float), stream);
  prep_w1_kernel<<<128, 64, 0, stream>>>(W1, W1f);
  attnpool_kernel<<<NBLK, 256, SMEM_BYTES, stream>>>(x, batch, W1f, b1, W2, b2, out, Zp, N);
  finalize_kernel<<<(out_size / 4 + 255) / 256, 256, 0, stream>>>(out, Zp, out_size / 4);
}

// Round 5
// 214.062 us; speedup vs baseline: 2.0574x; 1.3019x over previous
//
#include <hip/hip_runtime.h>
#include <stdint.h>

#define NBLOCKS 256
#define WPB 16                        // waves per block (1024 threads)
#define SLOTS (NBLOCKS * WPB)         // 4096 independent wave slots
#define SMEM_BYTES (131072 + 2048)    // 128KB B-frags + b1/W2

typedef __attribute__((ext_vector_type(8))) short bfrag_t;
typedef __attribute__((ext_vector_type(4))) float f32x4;

static __device__ __forceinline__ unsigned short f2bf(float f) {
  unsigned int u = __float_as_uint(f);
  u += 0x7fffu + ((u >> 16) & 1u);   // RNE
  return (unsigned short)(u >> 16);
}

static __device__ __forceinline__ float tanh_fast(float s) {
  // tanh(s) = 1 - 2/(1+e^{2s}); saturates at +-1, no clamp needed
  float e = __builtin_exp2f(s * 2.8853900817779268f);
  float r = __builtin_amdgcn_rcpf(1.f + e);
  return __builtin_fmaf(-2.f, r, 1.f);
}

// readlane for floats: BIT-cast, not value-cast (builtin is int-typed;
// passing float value-truncates — that was round 4's correctness bug)
static __device__ __forceinline__ float readlane_f(float v, int l) {
  return __uint_as_float(__builtin_amdgcn_readlane(__float_as_uint(v), l));
}

static __device__ __forceinline__ bfrag_t pack8(f32x4 a, f32x4 b) {
  union { bfrag_t v; unsigned int u[4]; } r;
  asm("v_cvt_pk_bf16_f32 %0, %1, %2" : "=v"(r.u[0]) : "v"(a[0]), "v"(a[1]));
  asm("v_cvt_pk_bf16_f32 %0, %1, %2" : "=v"(r.u[1]) : "v"(a[2]), "v"(a[3]));
  asm("v_cvt_pk_bf16_f32 %0, %1, %2" : "=v"(r.u[2]) : "v"(b[0]), "v"(b[1]));
  asm("v_cvt_pk_bf16_f32 %0, %1, %2" : "=v"(r.u[3]) : "v"(b[2]), "v"(b[3]));
  return r.v;
}

#define KEEPA(A) asm volatile("" : "+v"(A[0]), "+v"(A[1]), "+v"(A[2]), "+v"(A[3]), \
                                    "+v"(A[4]), "+v"(A[5]), "+v"(A[6]), "+v"(A[7]))

#define GLD16(gp, lp) __builtin_amdgcn_global_load_lds( \
    (const __attribute__((address_space(1))) void*)(gp), \
    (__attribute__((address_space(3))) void*)(lp), 16, 0, 0)

// Pre-swizzle W1 (f32 [256][256], k-major) into MFMA B-fragment order, bf16.
// W1f[((cc*8+kk)*64 + lane)*8 + j] = bf16(W1[kk*32 + 8*(lane>>4) + j][cc*16 + (lane&15)])
__global__ void prep_w1_kernel(const float* __restrict__ W1, unsigned short* __restrict__ W1f) {
  const int bx = blockIdx.x;   // cc*8 + kk, 0..127
  const int l = threadIdx.x;   // 0..63
  const int cc = bx >> 3, kk = bx & 7;
  const int h = cc * 16 + (l & 15);
  const int kbase = kk * 32 + ((l >> 4) << 3);
  bfrag_t pk;
#pragma unroll
  for (int j = 0; j < 8; ++j) pk[j] = (short)f2bf(W1[(size_t)(kbase + j) * 256 + h]);
  *(bfrag_t*)(W1f + (size_t)(bx * 64 + l) * 8) = pk;
}

__launch_bounds__(1024, 4)
__global__ void attnpool_kernel(const float* __restrict__ x,
                                const int* __restrict__ batch,
                                const unsigned short* __restrict__ W1f,
                                const float* __restrict__ b1,
                                const float* __restrict__ W2,
                                const float* __restrict__ b2,
                                float* __restrict__ out,   // raw weighted sums (zeroed)
                                float* __restrict__ Zp,    // softmax denominator (zeroed)
                                int N, int ntiles, int tps) {
  extern __shared__ char smem[];
  char*  Bl  = smem;                       // [128 frags][64 lanes][16B], frag-linear
  float* b1s = (float*)(smem + 131072);    // [256]
  float* w2s = (float*)(smem + 132096);    // [256]

  const int t = threadIdx.x;
  const int lane = t & 63;
  const int wv = t >> 6;
  const int l15 = lane & 15;
  const int hi = lane >> 4;

  // ---- prologue: stage W1f (frag-linear) + b1/W2 into LDS; ONE barrier ----
#pragma unroll
  for (int i = 0; i < 8; ++i) {
    const int f = wv * 8 + i;
    const unsigned short* src = W1f + (size_t)f * 512 + lane * 8;
    GLD16(src, Bl + f * 1024);
  }
  if (t < 256) { b1s[t] = b1[t]; w2s[t] = W2[t]; }
  __syncthreads();   // only barrier in the kernel

  const float b2c = b2[0];
  const int slot = blockIdx.x * WPB + wv;
  const int t0 = slot * tps;
  const int t1 = min(t0 + tps, ntiles);

  float zacc = 0.f;
  f32x4 pacc = {0.f, 0.f, 0.f, 0.f};
  int gcur = -1;
  const char* bwave = Bl + lane * 16;

  for (int tile = t0; tile < t1; ++tile) {
    const int R0 = tile * 32;

    // batch ids for this tile: lane r (r<32) holds batch[R0+r]
    int bid = 0;
    {
      int rg = min(R0 + (lane & 31), N - 1);
      bid = batch[rg];
    }

    // ---- A-frags: global f32 -> bf16 regs (full 32x256 tile across the wave) ----
    bfrag_t A0[8], A1[8];
    {
      const int r0g = min(R0 + l15, N - 1);
      const int r1g = min(R0 + 16 + l15, N - 1);
      const float* p0 = x + (size_t)r0g * 256 + hi * 8;
      const float* p1 = x + (size_t)r1g * 256 + hi * 8;
#pragma unroll
      for (int kk = 0; kk < 8; ++kk) {
        const f32x4 u0 = *(const f32x4*)(p0 + kk * 32);
        const f32x4 u1 = *(const f32x4*)(p0 + kk * 32 + 4);
        const f32x4 v0 = *(const f32x4*)(p1 + kk * 32);
        const f32x4 v1 = *(const f32x4*)(p1 + kk * 32 + 4);
        A0[kk] = pack8(u0, u1);
        A1[kk] = pack8(v0, v1);
      }
    }

    // ---- score: cc-outer MFMA, B from LDS (conflict-free lane-linear) ----
    float s0[4] = {0.f, 0.f, 0.f, 0.f};
    float s1[4] = {0.f, 0.f, 0.f, 0.f};
#pragma unroll 2
    for (int cc = 0; cc < 16; ++cc) {
      KEEPA(A0);  // pin A in VGPRs: remat/sink into the loop is impossible
      KEEPA(A1);
      const char* bb = bwave + cc * 8192;
      f32x4 acc0 = {0.f, 0.f, 0.f, 0.f}, acc1 = {0.f, 0.f, 0.f, 0.f};
#pragma unroll
      for (int kk = 0; kk < 8; ++kk) {
        const bfrag_t Bk = *(const bfrag_t*)(bb + kk * 1024);
        acc0 = __builtin_amdgcn_mfma_f32_16x16x32_bf16(A0[kk], Bk, acc0, 0, 0, 0);
        acc1 = __builtin_amdgcn_mfma_f32_16x16x32_bf16(A1[kk], Bk, acc1, 0, 0, 0);
      }
      const float b1c = b1s[cc * 16 + l15];
      const float w2c = w2s[cc * 16 + l15];
#pragma unroll
      for (int r = 0; r < 4; ++r) {
        s0[r] += tanh_fast(acc0[r] + b1c) * w2c;
        s1[r] += tanh_fast(acc1[r] + b1c) * w2c;
      }
    }

    // ---- reduce over the 16-lane col groups; w = exp(score + b2) ----
    float w0[4], w1[4];
#pragma unroll
    for (int r = 0; r < 4; ++r) {
      float v0 = s0[r], v1 = s1[r];
      v0 += __shfl_xor(v0, 1); v0 += __shfl_xor(v0, 2);
      v0 += __shfl_xor(v0, 4); v0 += __shfl_xor(v0, 8);
      v1 += __shfl_xor(v1, 1); v1 += __shfl_xor(v1, 2);
      v1 += __shfl_xor(v1, 4); v1 += __shfl_xor(v1, 8);
      w0[r] = (R0 + hi * 4 + r < N) ? __expf(v0 + b2c) : 0.f;
      w1[r] = (R0 + 16 + hi * 4 + r < N) ? __expf(v1 + b2c) : 0.f;
    }
    // Z partial: rows are unique per (hi,r); reduce across hi only
    {
      float z = w0[0] + w0[1] + w0[2] + w0[3] + w1[0] + w1[1] + w1[2] + w1[3];
      z += __shfl_xor(z, 16);
      z += __shfl_xor(z, 32);
      zacc += z;
    }

    // ---- pool: lane owns cols 4*lane..4*lane+3; w/g broadcast via readlane ----
    const float* xp = x + (size_t)R0 * 256 + lane * 4;
#pragma unroll
    for (int r = 0; r < 32; ++r) {
      const float wr = (r < 16) ? readlane_f(w0[r & 3], ((r >> 2) & 3) * 16)
                                : readlane_f(w1[r & 3], ((r >> 2) & 3) * 16);
      const int g = __builtin_amdgcn_readlane(bid, r);
      if (g != gcur) {
        if (gcur >= 0) {
          float* po = out + (size_t)gcur * 256 + lane * 4;
          atomicAdd(po + 0, pacc[0]); atomicAdd(po + 1, pacc[1]);
          atomicAdd(po + 2, pacc[2]); atomicAdd(po + 3, pacc[3]);
        }
        pacc[0] = pacc[1] = pacc[2] = pacc[3] = 0.f;
        gcur = g;
      }
      const f32x4 xv = *(const f32x4*)(xp + (size_t)r * 256);
      pacc[0] = __builtin_fmaf(wr, xv[0], pacc[0]);
      pacc[1] = __builtin_fmaf(wr, xv[1], pacc[1]);
      pacc[2] = __builtin_fmaf(wr, xv[2], pacc[2]);
      pacc[3] = __builtin_fmaf(wr, xv[3], pacc[3]);
    }
  }

  if (gcur >= 0) {
    float* po = out + (size_t)gcur * 256 + lane * 4;
    atomicAdd(po + 0, pacc[0]); atomicAdd(po + 1, pacc[1]);
    atomicAdd(po + 2, pacc[2]); atomicAdd(po + 3, pacc[3]);
  }
  if (lane == 0 && zacc != 0.f) atomicAdd(Zp, zacc);
}

__global__ void finalize_kernel(float* __restrict__ out, const float* __restrict__ Zp, int n4) {
  const int i = blockIdx.x * blockDim.x + threadIdx.x;
  if (i < n4) {
    const float zi = 1.f / Zp[0];
    f32x4* p = (f32x4*)out;
    f32x4 v = p[i];
    v[0] *= zi; v[1] *= zi; v[2] *= zi; v[3] *= zi;
    p[i] = v;
  }
}

extern "C" void kernel_launch(void* const* d_in, const int* in_sizes, int n_in,
                              void* d_out, int out_size, void* d_ws, size_t ws_size,
                              hipStream_t stream) {
  const float* x  = (const float*)d_in[0];
  const int* batch = (const int*)d_in[1];
  const float* W1 = (const float*)d_in[2];
  const float* b1 = (const float*)d_in[3];
  const float* W2 = (const float*)d_in[4];
  const float* b2 = (const float*)d_in[5];
  float* out = (float*)d_out;
  const int N = in_sizes[1];

  unsigned short* W1f = (unsigned short*)d_ws;          // 128 KB
  float* Zp = (float*)((char*)d_ws + 131072);           // 4 B

  static int attr_done = 0;  // host-side only; idempotent attribute, not kernel state
  if (!attr_done) {
    hipFuncSetAttribute((const void*)attnpool_kernel,
                        hipFuncAttributeMaxDynamicSharedMemorySize, SMEM_BYTES);
    attr_done = 1;
  }

  const int ntiles = (N + 31) / 32;
  const int tps = (ntiles + SLOTS - 1) / SLOTS;

  hipMemsetAsync(d_out, 0, (size_t)out_size * sizeof(float), stream);
  hipMemsetAsync(Zp, 0, sizeof(float), stream);
  prep_w1_kernel<<<128, 64, 0, stream>>>(W1, W1f);
  attnpool_kernel<<<NBLOCKS, 1024, SMEM_BYTES, stream>>>(x, batch, W1f, b1, W2, b2,
                                                         out, Zp, N, ntiles, tps);
  finalize_kernel<<<(out_size / 4 + 255) / 256, 256, 0, stream>>>(out, Zp, out_size / 4);
}